// Round 4
// baseline (5103.032 us; speedup 1.0000x reference)
//
#include <hip/hip_runtime.h>

typedef unsigned short u16;
typedef unsigned int u32;

#define NB 8
#define NPTS 4096
#define MSEL 2048
#define NCENT (NB*MSEL)
#define KNBR 64
#define FEAT 64
#define FIN 67
#define HH 64
#define FOUT 128
#define CAND_CAP 512

// ---------------------------------------------------------------------------
// Kernel 1: exact FPS, one block per cloud. _rn ops in numpy's sum order
// ((dx^2+dy^2)+dz^2), first-occurrence argmax tie-break -> matches the np
// reference's f32 FPS decisions bit-exactly. All f32 I/O.
// ---------------------------------------------------------------------------
__global__ __launch_bounds__(256) void fps_kernel(const float* __restrict__ pos,
        int* __restrict__ sel, float* __restrict__ pos_out,
        float* __restrict__ batch_out) {
    __shared__ float px[NPTS], py[NPTS], pz[NPTS];
    __shared__ float redv[4];
    __shared__ int   redi[4];
    const int b = blockIdx.x, t = threadIdx.x;
    const int lane = t & 63, wid = t >> 6;
    const float* pb = pos + (long)b * NPTS * 3;

    for (int i = t; i < NPTS; i += 256) {
        px[i] = pb[i*3+0];
        py[i] = pb[i*3+1];
        pz[i] = pb[i*3+2];
    }
    __syncthreads();

    float rx[16], ry[16], rz[16], md[16];
    #pragma unroll
    for (int j = 0; j < 16; ++j) {
        int i = t + 256*j;
        rx[j] = px[i]; ry[j] = py[i]; rz[j] = pz[i];
        md[j] = __builtin_inff();
    }

    int cur = 0;
    for (int s = 0; s < MSEL; ++s) {
        float cx = px[cur], cy = py[cur], cz = pz[cur];
        if (t == 0) {
            int g = b * MSEL + s;
            sel[g] = cur;
            pos_out[g*3+0] = cx;
            pos_out[g*3+1] = cy;
            pos_out[g*3+2] = cz;
            batch_out[g] = (float)b;
        }
        float bv = -1.0f; int bi = 0;
        #pragma unroll
        for (int j = 0; j < 16; ++j) {
            float dx = __fsub_rn(rx[j], cx);
            float dy = __fsub_rn(ry[j], cy);
            float dz = __fsub_rn(rz[j], cz);
            float d  = __fadd_rn(__fadd_rn(__fmul_rn(dx,dx), __fmul_rn(dy,dy)),
                                 __fmul_rn(dz,dz));
            float m = fminf(md[j], d);
            md[j] = m;
            if (m > bv) { bv = m; bi = t + 256*j; }   // strict >: first occurrence
        }
        #pragma unroll
        for (int off = 32; off >= 1; off >>= 1) {
            float ov = __shfl_down(bv, off, 64);
            int   oi = __shfl_down(bi, off, 64);
            if (ov > bv || (ov == bv && oi < bi)) { bv = ov; bi = oi; }
        }
        if (lane == 0) { redv[wid] = bv; redi[wid] = bi; }
        __syncthreads();
        float v = redv[0]; int ii = redi[0];
        #pragma unroll
        for (int w = 1; w < 4; ++w) {
            float ov = redv[w]; int oi = redi[w];
            if (ov > v || (ov == v && oi < ii)) { v = ov; ii = oi; }
        }
        cur = ii;
        __syncthreads();
    }
}

// ---------------------------------------------------------------------------
// Kernel 2: fused radius + PointNetConv + max-pool. One 128-thread block per
// centroid, structure unchanged from round 3 (naive, correct-by-inspection);
// only the I/O dtype changed to f32.
// ---------------------------------------------------------------------------
__global__ __launch_bounds__(128) void conv_kernel(const float* __restrict__ x,
        const float* __restrict__ pos, const int* __restrict__ sel,
        const float* __restrict__ W1, const float* __restrict__ b1,
        const float* __restrict__ W2, const float* __restrict__ b2,
        const float* __restrict__ W3, const float* __restrict__ b3,
        float* __restrict__ xout) {
    __shared__ float feat[64][68];
    __shared__ float h1[64][64];
    __shared__ float h2[64][64];
    __shared__ float cdv[CAND_CAP];
    __shared__ int   cixv[CAND_CAP];
    __shared__ int   snbr[KNBR];
    __shared__ int   sc[2];
    const int c = blockIdx.x, t = threadIdx.x;   // t in [0,128)
    const int b = c >> 11;
    const float* pb = pos + (long)b * NPTS * 3;
    const int j0 = sel[c];
    const float qx = pb[j0*3+0], qy = pb[j0*3+1], qz = pb[j0*3+2];
    if (t == 0) { sc[0] = 0; sc[1] = 0; }
    __syncthreads();

    // ---- radius gather (f32 _rn, numpy order); (q-p)^2 == (p-q)^2 exactly
    const float R2 = (float)(0.15 * 0.15);
    for (int it = 0; it < NPTS/128; ++it) {
        int i = t + 128*it;
        float dx = __fsub_rn(qx, pb[i*3+0]);
        float dy = __fsub_rn(qy, pb[i*3+1]);
        float dz = __fsub_rn(qz, pb[i*3+2]);
        float d2 = __fadd_rn(__fadd_rn(__fmul_rn(dx,dx), __fmul_rn(dy,dy)),
                             __fmul_rn(dz,dz));
        if (d2 <= R2) {
            int slot = atomicAdd(&sc[0], 1);
            if (slot < CAND_CAP) { cdv[slot] = d2; cixv[slot] = i; }
        }
    }
    __syncthreads();
    int C = sc[0]; if (C > CAND_CAP) C = CAND_CAP;
    int cnt;
    if (C <= KNBR) {
        for (int e = t; e < C; e += 128) snbr[e] = cixv[e];
        cnt = C;
    } else {
        // lexicographic (d2, idx) rank-select == stable top_k neighbor SET
        for (int e = t; e < C; e += 128) {
            float de = cdv[e]; int ie = cixv[e];
            int rank = 0;
            for (int f = 0; f < C; ++f) {
                float df = cdv[f]; int jf = cixv[f];
                rank += (df < de || (df == de && jf < ie)) ? 1 : 0;
            }
            if (rank < KNBR) {
                int slot = atomicAdd(&sc[1], 1);
                snbr[slot] = ie;
            }
        }
        cnt = KNBR;
    }
    __syncthreads();

    // ---- stage features [x_j || pos_j - q]
    for (int k = 0; k < cnt; ++k) {
        int j = snbr[k];
        const float* xr = x + ((long)b*NPTS + j) * FEAT;
        for (int f = t; f < FIN; f += 128) {
            float v;
            if (f < 64)       v = xr[f];
            else if (f == 64) v = __fsub_rn(pb[j*3+0], qx);
            else if (f == 65) v = __fsub_rn(pb[j*3+1], qy);
            else              v = __fsub_rn(pb[j*3+2], qz);
            feat[k][f] = v;
        }
    }
    __syncthreads();

    // ---- layer 1: h1[k][t] = relu(b1[t] + sum_f feat[k][f]*W1[f][t])
    if (t < 64) {
        for (int k = 0; k < cnt; ++k) {
            float a = b1[t];
            for (int f = 0; f < FIN; ++f)
                a = fmaf(feat[k][f], W1[(long)f*HH + t], a);
            h1[k][t] = fmaxf(a, 0.0f);
        }
    }
    __syncthreads();

    // ---- layer 2
    if (t < 64) {
        for (int k = 0; k < cnt; ++k) {
            float a = b2[t];
            for (int f = 0; f < HH; ++f)
                a = fmaf(h1[k][f], W2[(long)f*HH + t], a);
            h2[k][t] = fmaxf(a, 0.0f);
        }
    }
    __syncthreads();

    // ---- layer 3 + max-pool: thread t owns output channel t
    float mx = 0.0f;   // relu >= 0 and cnt >= 1 -> 0 is the identity
    for (int k = 0; k < cnt; ++k) {
        float a = b3[t];
        for (int f = 0; f < HH; ++f)
            a = fmaf(h2[k][f], W3[(long)f*FOUT + t], a);
        mx = fmaxf(mx, fmaxf(a, 0.0f));
    }
    xout[(long)c*FOUT + t] = mx;
}

// ---------------------------------------------------------------------------
extern "C" void kernel_launch(void* const* d_in, const int* in_sizes, int n_in,
                              void* d_out, int out_size, void* d_ws, size_t ws_size,
                              hipStream_t stream) {
    const float* x   = (const float*)d_in[0];
    const float* pos = (const float*)d_in[1];
    // d_in[2] = batch (deterministic, unused)
    const float* W1 = (const float*)d_in[3];
    const float* b1 = (const float*)d_in[4];
    const float* W2 = (const float*)d_in[5];
    const float* b2 = (const float*)d_in[6];
    const float* W3 = (const float*)d_in[7];
    const float* b3 = (const float*)d_in[8];

    float* out       = (float*)d_out;
    float* xout      = out;                          // [16384,128] f32
    float* pos_out   = out + (long)NCENT * FOUT;     // [16384,3]   f32
    float* batch_out = pos_out + (long)NCENT * 3;    // [16384]     f32

    int* sel = (int*)d_ws;                           // 16384 ints

    fps_kernel<<<NB, 256, 0, stream>>>(pos, sel, pos_out, batch_out);
    conv_kernel<<<NCENT, 128, 0, stream>>>(x, pos, sel,
                                           W1, b1, W2, b2, W3, b3, xout);
}